// Round 3
// baseline (362.406 us; speedup 1.0000x reference)
//
#include <hip/hip_runtime.h>
#include <hip/hip_bf16.h>

#define D 1024
#define SLEN 2048
#define BS 16
#define MROWS (BS*SLEN)   // 32768

typedef __attribute__((ext_vector_type(8))) short short8;
typedef __attribute__((ext_vector_type(4))) float f32x4;

__device__ __forceinline__ short f2bf(float f) {
  __hip_bfloat16 h = __float2bfloat16(f);
  return __builtin_bit_cast(short, h);
}

// non-temporal float4 load: states is pure streaming in the GEMM (zero reuse
// there) -> bypass L2 retention so the 2 MB WkT stays L2-resident for B.
__device__ __forceinline__ float4 ntload4(const float* p) {
  f32x4 v = __builtin_nontemporal_load((const f32x4*)p);
  float4 r; r.x = v.x; r.y = v.y; r.z = v.z; r.w = v.w; return r;
}

// ---------------- Kernel 1: Wk (k,n) fp32 -> blocked bf16 WkT ----------------
// WkT[(u*1024 + n)*8 + j] = bf16(Wk[(u*8+j)*1024 + n]), u=0..127.
__global__ __launch_bounds__(256) void wk_prep(const float* __restrict__ Wk,
                                               short* __restrict__ WkT) {
  const int g = blockIdx.x;        // 0..127
  const int t = threadIdx.x;
#pragma unroll
  for (int it = 0; it < 4; ++it) {
    const int n = it*256 + t;
    short8 p;
#pragma unroll
    for (int j = 0; j < 8; ++j)
      p[j] = f2bf(Wk[(size_t)(g*8 + j)*D + n]);
    *(short8*)(WkT + ((size_t)g*D + n)*8) = p;
  }
}

// ---------------- Kernel 2: energy GEMM, occupancy-first ----------------
// R0/R2 post-mortem: 132KB LDS *and* ~240 unified regs/wave BOTH capped the
// kernel at 2 waves/SIMD; MfmaUtil=30% matched that model exactly, and no
// prefetch restructure at that occupancy moved anything.
// v3: 1024-thread block (16 waves), wave = 64 rows x 64 cols -> acc 64 regs;
// __launch_bounds__(1024,4) forces <=128 unified regs -> 4 waves/SIMD.
// A staged in TWO K-halves (ping-pong LDS, 2x65KB=130KB, 1 block/CU), half-1
// loads issued mid-half-0 (T14: ~8 ksteps of MFMA cover HBM latency), so the
// staging HBM burst overlaps compute. B streamed from L2 per kstep.
__global__ __launch_bounds__(1024, 4) void energy_gemm(
    const float* __restrict__ states, const short* __restrict__ WkT,
    const float* __restrict__ bk, const float* __restrict__ We,
    float* __restrict__ eraw, float* __restrict__ attn)
{
  // two half-K buffers: half h at Al + h*33280 shorts; slot(row,u)=row*65+u,
  // u=0..63 (512 K per half, 8 K-elems per u-unit). 133,120 B total.
  __shared__ short Al[2 * 64 * 65 * 8];

  const int tid  = threadIdx.x;
  const int w    = tid >> 6;        // wave 0..15 -> col group w*64
  const int lane = tid & 63;
  const int quad = lane >> 4;       // k-unit within 32-chunk
  const int l16  = lane & 15;
  const int m0   = blockIdx.x * 64;

  // zero-init attn region (read-modify-write target of attn_fused)
  if (blockIdx.x < BS && tid < 256) {
    f32x4 z = {0.f, 0.f, 0.f, 0.f};
    *(f32x4*)(attn + (size_t)blockIdx.x*D + tid*4) = z;
  }

  // staging mapping: thread -> (row, 32-float segment)
  const int srow = tid >> 4;        // 0..63
  const int sseg = tid & 15;        // 0..15
  const float* Ag = states + (size_t)(m0 + srow)*D + sseg*32;

  float4 stg[8];

#define STAGE_LOAD4(h, off)                                              \
  {                                                                      \
    _Pragma("unroll")                                                    \
    for (int i = 0; i < 4; ++i)                                          \
      stg[(off) + i] = ntload4(Ag + (h)*512 + ((off) + i)*4);            \
  }

#define STAGE_WRITE(h)                                                   \
  {                                                                      \
    _Pragma("unroll")                                                    \
    for (int j = 0; j < 4; ++j) {                                        \
      short8 p;                                                          \
      p[0]=f2bf(stg[2*j].x);   p[1]=f2bf(stg[2*j].y);                    \
      p[2]=f2bf(stg[2*j].z);   p[3]=f2bf(stg[2*j].w);                    \
      p[4]=f2bf(stg[2*j+1].x); p[5]=f2bf(stg[2*j+1].y);                  \
      p[6]=f2bf(stg[2*j+1].z); p[7]=f2bf(stg[2*j+1].w);                  \
      *(short8*)(Al + (size_t)(h)*33280 +                                \
                 ((size_t)srow*65 + sseg*4 + j)*8) = p;                  \
    }                                                                    \
  }

  // fragment bases
  const short* abase = Al + ((size_t)l16*65 + quad)*8;   // + h*33280 + mi*8320 + ks*32
  const short* bbase = WkT + ((size_t)quad*D + w*64 + l16)*8;  // + ksg*32768 + ni*128

  f32x4 acc[4][4];
#pragma unroll
  for (int mi = 0; mi < 4; ++mi)
#pragma unroll
    for (int ni = 0; ni < 4; ++ni)
      acc[mi][ni] = (f32x4){0.f, 0.f, 0.f, 0.f};

#define LOADA(h, ks, buf)                                                \
  {                                                                      \
    const short* ap = abase + (h)*33280 + (ks)*32;                       \
    _Pragma("unroll")                                                    \
    for (int mi = 0; mi < 4; ++mi)                                       \
      buf[mi] = *(const short8*)(ap + mi*8320);                          \
  }

#define LOADB(ksg, buf)                                                  \
  {                                                                      \
    const short* bp = bbase + (size_t)(ksg)*32768;                       \
    _Pragma("unroll")                                                    \
    for (int ni = 0; ni < 4; ++ni)                                       \
      buf[ni] = *(const short8*)(bp + ni*128);                           \
  }

#define MFMAS(fa, fb)                                                    \
  {                                                                      \
    __builtin_amdgcn_s_setprio(1);                                       \
    _Pragma("unroll")                                                    \
    for (int mi = 0; mi < 4; ++mi)                                       \
      _Pragma("unroll")                                                  \
      for (int ni = 0; ni < 4; ++ni)                                     \
        acc[mi][ni] = __builtin_amdgcn_mfma_f32_16x16x32_bf16(           \
            fa[mi], fb[ni], acc[mi][ni], 0, 0, 0);                       \
    __builtin_amdgcn_s_setprio(0);                                       \
  }

  // ---- prologue: stage half 0 ----
  STAGE_LOAD4(0, 0); STAGE_LOAD4(0, 4);
  STAGE_WRITE(0);
  __syncthreads();

  short8 fa[4], fb[4];

  // ---- half 0 compute; issue half-1 loads mid-way (T14 issue-early) ----
#pragma unroll
  for (int ks = 0; ks < 16; ++ks) {
    if (ks == 8)  STAGE_LOAD4(1, 0);
    if (ks == 12) STAGE_LOAD4(1, 4);
    LOADA(0, ks, fa);
    LOADB(ks, fb);
    MFMAS(fa, fb);
  }

  // ---- write half 1 (vmcnt auto-inserted for stg), one barrier ----
  STAGE_WRITE(1);
  __syncthreads();

  // ---- half 1 compute ----
#pragma unroll
  for (int ks = 0; ks < 16; ++ks) {
    LOADA(1, ks, fa);
    LOADB(16 + ks, fb);
    MFMAS(fa, fb);
  }

  // ---- epilogue: esum[row] += tanh(relu(c + bk[n])) * We_k[n] ----
  float esum[16];
#pragma unroll
  for (int q = 0; q < 16; ++q) esum[q] = 0.f;
#pragma unroll
  for (int ni = 0; ni < 4; ++ni) {
    const int n = w*64 + ni*16 + l16;
    const float bkv = bk[n];
    const float wev = We[D + n];
#pragma unroll
    for (int mi = 0; mi < 4; ++mi)
#pragma unroll
      for (int r = 0; r < 4; ++r) {
        float x = acc[mi][ni][r] + bkv;
        x = fmaxf(x, 0.f);
        float ex = __expf(2.f * x);
        float th = 1.f - 2.f/(ex + 1.f);
        esum[mi*4 + r] += th * wev;
      }
  }
  // sum across the 16 l16-lanes (xor 1,2,4,8 stays within lane&15 groups)
#pragma unroll
  for (int dd = 1; dd < 16; dd <<= 1)
#pragma unroll
    for (int q = 0; q < 16; ++q)
      esum[q] += __shfl_xor(esum[q], dd, 64);

  __syncthreads();                    // all waves done reading Al
  float* red = (float*)Al;            // [64 rows][16 waves]
  if (l16 == 0) {
#pragma unroll
    for (int mi = 0; mi < 4; ++mi)
#pragma unroll
      for (int r = 0; r < 4; ++r)
        red[(mi*16 + quad*4 + r)*16 + w] = esum[mi*4 + r];
  }
  __syncthreads();
  if (tid < 64) {
    float s = 0.f;
#pragma unroll
    for (int wi = 0; wi < 16; ++wi) s += red[tid*16 + wi];
    eraw[m0 + tid] = s;
  }
#undef STAGE_LOAD4
#undef STAGE_WRITE
#undef LOADA
#undef LOADB
#undef MFMAS
}

// -------- Kernel 3: fused softmax + attn accumulation (one launch) ----------
__global__ __launch_bounds__(512) void attn_fused(
    const float* __restrict__ states, const float* __restrict__ eraw,
    float* __restrict__ wts, float* __restrict__ attn)
{
  const int sc = blockIdx.x;        // 0..31 -> rows sc*64 .. sc*64+63
  const int b  = blockIdx.y;        // 0..15
  const int t  = threadIdx.x;
  const int wv = t >> 6;
  const int lane = t & 63;

  __shared__ float  redm[8];
  __shared__ float  reds[8];
  __shared__ float  wsh[64];
  __shared__ float4 part[256];

  // ---- redundant softmax stats over the full 2048-row energy ----
  float v[4];
  float m = -1e30f;
#pragma unroll
  for (int j = 0; j < 4; ++j) {
    v[j] = eraw[(size_t)b*SLEN + j*512 + t];
    m = fmaxf(m, v[j]);
  }
#pragma unroll
  for (int dd = 1; dd < 64; dd <<= 1) m = fmaxf(m, __shfl_xor(m, dd, 64));
  if (lane == 0) redm[wv] = m;
  __syncthreads();
  float m2 = redm[0];
#pragma unroll
  for (int i = 1; i < 8; ++i) m2 = fmaxf(m2, redm[i]);

  float sum = 0.f;
#pragma unroll
  for (int j = 0; j < 4; ++j) sum += __expf(v[j] - m2);
#pragma unroll
  for (int dd = 1; dd < 64; dd <<= 1) sum += __shfl_xor(sum, dd, 64);
  if (lane == 0) reds[wv] = sum;
  __syncthreads();
  float s2 = 0.f;
#pragma unroll
  for (int i = 0; i < 8; ++i) s2 += reds[i];
  const float inv = 1.f / s2;

  // ---- weights for this block's 64 rows ----
  if (t < 64) {
    const float wvv = __expf(eraw[(size_t)b*SLEN + sc*64 + t] - m2) * inv;
    wts[(size_t)b*SLEN + sc*64 + t] = wvv;
    wsh[t] = wvv;
  }
  __syncthreads();

  // ---- accumulate attn partial ----
  const int dq = (t & 255) << 2;    // d offset (float4)
  const int ss = t >> 8;            // s-half 0/1
  const float* sp = states + ((size_t)b*SLEN + sc*64 + ss*32)*D + dq;
  float ax = 0.f, ay = 0.f, az = 0.f, aw = 0.f;
#pragma unroll
  for (int s = 0; s < 32; ++s) {
    float4 x = *(const float4*)(sp + (size_t)s*D);
    const float wvv = wsh[ss*32 + s];
    ax = fmaf(wvv, x.x, ax);
    ay = fmaf(wvv, x.y, ay);
    az = fmaf(wvv, x.z, az);
    aw = fmaf(wvv, x.w, aw);
  }

  if (ss) part[t & 255] = (float4){ax, ay, az, aw};
  __syncthreads();
  if (!ss) {
    const float4 o = part[t];
    float* p = attn + (size_t)b*D + dq;
    atomicAdd(p + 0, ax + o.x);
    atomicAdd(p + 1, ay + o.y);
    atomicAdd(p + 2, az + o.z);
    atomicAdd(p + 3, aw + o.w);
  }
}

extern "C" void kernel_launch(void* const* d_in, const int* in_sizes, int n_in,
                              void* d_out, int out_size, void* d_ws, size_t ws_size,
                              hipStream_t stream) {
  // inputs: 0=query 1=states 2=Wq 3=bq 4=Wk 5=bk 6=We 7=be
  // q-path terms are constant per softmax row -> cancel; dead code.
  const float* states = (const float*)d_in[1];
  const float* Wk     = (const float*)d_in[4];
  const float* bk     = (const float*)d_in[5];
  const float* We     = (const float*)d_in[6];
  float* out = (float*)d_out;            // [0:32768) attn_weights, [32768:49152) attn

  short* WkT  = (short*)d_ws;                                   // 2 MB
  float* eraw = (float*)((char*)d_ws + (size_t)D*D*sizeof(short));  // 128 KB

  (void)in_sizes; (void)n_in; (void)out_size; (void)ws_size;

  wk_prep<<<128, 256, 0, stream>>>(Wk, WkT);
  energy_gemm<<<MROWS/64, 1024, 0, stream>>>(states, WkT, bk, We, eraw, out + MROWS);
  attn_fused<<<dim3(32, BS), 512, 0, stream>>>(states, eraw, out, out + MROWS);
}

// Round 4
// 274.196 us; speedup vs baseline: 1.3217x; 1.3217x over previous
//
#include <hip/hip_runtime.h>
#include <hip/hip_bf16.h>

#define D 1024
#define SLEN 2048
#define BS 16
#define MROWS (BS*SLEN)   // 32768
#define NCHUNK (MROWS/64) // 512 chunks of 64 s-rows

typedef __attribute__((ext_vector_type(8))) short short8;
typedef __attribute__((ext_vector_type(4))) float f32x4;

__device__ __forceinline__ short f2bf(float f) {
  __hip_bfloat16 h = __float2bfloat16(f);
  return __builtin_bit_cast(short, h);
}

// non-temporal float4 load: states is read EXACTLY ONCE now (GEMM staging);
// bypass L2 retention so the 2 MB WkT stays L2-resident for the B stream.
__device__ __forceinline__ float4 ntload4(const float* p) {
  f32x4 v = __builtin_nontemporal_load((const f32x4*)p);
  float4 r; r.x = v.x; r.y = v.y; r.z = v.z; r.w = v.w; return r;
}

// ---------------- Kernel 1: Wk (k,n) fp32 -> blocked bf16 WkT ----------------
// WkT[(u*1024 + n)*8 + j] = bf16(Wk[(u*8+j)*1024 + n]), u=0..127.
__global__ __launch_bounds__(256) void wk_prep(const float* __restrict__ Wk,
                                               short* __restrict__ WkT) {
  const int g = blockIdx.x;        // 0..127
  const int t = threadIdx.x;
#pragma unroll
  for (int it = 0; it < 4; ++it) {
    const int n = it*256 + t;
    short8 p;
#pragma unroll
    for (int j = 0; j < 8; ++j)
      p[j] = f2bf(Wk[(size_t)(g*8 + j)*D + n]);
    *(short8*)(WkT + ((size_t)g*D + n)*8) = p;
  }
}

// ------- Kernel 2: energy GEMM + FUSED chunk-local softmax/attn partial -----
// R0's proven structure (97us, 2 waves/SIMD, barrier-free K-loop) + flash-
// style epilogue: this block's 64 e-values -> chunk max m_c, p=exp(e-m_c),
// sumexp_c, and partial_d = sum_s p_s * A_lds[s][d] read straight from the
// LDS bf16 copy of states. Kills the 128 MB second read of states that the
// old attn kernel did (the dominant non-GEMM cost, ~100us).
__global__ __launch_bounds__(512, 2) void energy_gemm(
    const float* __restrict__ states, const short* __restrict__ WkT,
    const float* __restrict__ bk, const float* __restrict__ We,
    float* __restrict__ eraw, float* __restrict__ pattn,
    float* __restrict__ cmax, float* __restrict__ csum)
{
  __shared__ short Al[64 * 129 * 8];   // 132 KB: slot(row,u) = row*129 + u
  __shared__ float red2[64 * 8];       // cross-wave e reduction (NOT aliasing Al)
  __shared__ float pfin[64];           // p_s = exp(e_s - m_c)

  const int tid  = threadIdx.x;
  const int w    = tid >> 6;        // wave 0..7 -> col group w*128
  const int lane = tid & 63;
  const int quad = lane >> 4;       // k-unit within 32-chunk
  const int l16  = lane & 15;
  const int g    = blockIdx.x;      // chunk id 0..511
  const int m0   = g * 64;

  // ---- one-time A staging: 64 rows x 1024 k, fp32 -> bf16 (non-temporal) ----
  {
    const int row = tid >> 3;
    const int u0  = tid & 7;
    const float* Ag = states + (size_t)(m0 + row)*D;
#pragma unroll
    for (int i = 0; i < 16; ++i) {
      const int u = u0 + i*8;
      float4 x0 = ntload4(Ag + u*8);
      float4 x1 = ntload4(Ag + u*8 + 4);
      short8 p;
      p[0]=f2bf(x0.x); p[1]=f2bf(x0.y); p[2]=f2bf(x0.z); p[3]=f2bf(x0.w);
      p[4]=f2bf(x1.x); p[5]=f2bf(x1.y); p[6]=f2bf(x1.z); p[7]=f2bf(x1.w);
      *(short8*)(Al + ((size_t)row*129 + u)*8) = p;
    }
  }
  __syncthreads();

  f32x4 acc[2][4][4];
#pragma unroll
  for (int nc = 0; nc < 2; ++nc)
#pragma unroll
    for (int mi = 0; mi < 4; ++mi)
#pragma unroll
      for (int ni = 0; ni < 4; ++ni)
        acc[nc][mi][ni] = (f32x4){0.f, 0.f, 0.f, 0.f};

  const short* bbase = WkT + ((size_t)quad*D + w*128 + l16)*8;   // + ks*32768 + nc*512 + ni*128
  const short* abase = Al + ((size_t)l16*129 + quad)*8;          // + mi*16512 + ks*32

#define LOADB(ks, buf)                                                   \
  {                                                                      \
    const short* bp = bbase + (size_t)(ks)*32768;                        \
    _Pragma("unroll")                                                    \
    for (int nc = 0; nc < 2; ++nc)                                       \
      _Pragma("unroll")                                                  \
      for (int ni = 0; ni < 4; ++ni)                                     \
        buf[nc*4 + ni] = *(const short8*)(bp + nc*512 + ni*128);         \
  }

#define LOADA(ks, buf)                                                   \
  {                                                                      \
    _Pragma("unroll")                                                    \
    for (int mi = 0; mi < 4; ++mi)                                       \
      buf[mi] = *(const short8*)(abase + mi*16512 + (ks)*32);            \
  }

#define MFMAS(fa, fb)                                                    \
  {                                                                      \
    _Pragma("unroll")                                                    \
    for (int nc = 0; nc < 2; ++nc)                                       \
      _Pragma("unroll")                                                  \
      for (int mi = 0; mi < 4; ++mi)                                     \
        _Pragma("unroll")                                                \
        for (int ni = 0; ni < 4; ++ni)                                   \
          acc[nc][mi][ni] = __builtin_amdgcn_mfma_f32_16x16x32_bf16(     \
              fa[mi], fb[nc*4 + ni], acc[nc][mi][ni], 0, 0, 0);          \
  }

  short8 fa0[4], fa1[4], fb0[8], fb1[8];
  LOADA(0, fa0); LOADB(0, fb0);
#pragma unroll
  for (int kk = 0; kk < 16; ++kk) {
    LOADA(2*kk + 1, fa1); LOADB(2*kk + 1, fb1);
    MFMAS(fa0, fb0);
    if (kk < 15) { LOADA(2*kk + 2, fa0); LOADB(2*kk + 2, fb0); }
    MFMAS(fa1, fb1);
  }

  // ---- epilogue 1: esum[row] += tanh(relu(c + bk[n])) * We_k[n] ----
  float esum[16];
#pragma unroll
  for (int q = 0; q < 16; ++q) esum[q] = 0.f;
#pragma unroll
  for (int nc = 0; nc < 2; ++nc)
#pragma unroll
    for (int ni = 0; ni < 4; ++ni) {
      const int n = w*128 + nc*64 + ni*16 + l16;
      const float bkv = bk[n];
      const float wev = We[D + n];
#pragma unroll
      for (int mi = 0; mi < 4; ++mi)
#pragma unroll
        for (int r = 0; r < 4; ++r) {
          float x = acc[nc][mi][ni][r] + bkv;
          x = fmaxf(x, 0.f);
          float ex = __expf(2.f * x);
          float th = 1.f - 2.f/(ex + 1.f);
          esum[mi*4 + r] += th * wev;
        }
    }
#pragma unroll
  for (int dd = 1; dd < 16; dd <<= 1)
#pragma unroll
    for (int q = 0; q < 16; ++q)
      esum[q] += __shfl_xor(esum[q], dd, 64);

  if (l16 == 0) {
#pragma unroll
    for (int mi = 0; mi < 4; ++mi)
#pragma unroll
      for (int r = 0; r < 4; ++r)
        red2[(mi*16 + quad*4 + r)*8 + w] = esum[mi*4 + r];
  }
  __syncthreads();

  // ---- epilogue 2: chunk softmax stats (wave 0, 64 lanes = 64 rows) ----
  if (tid < 64) {
    float e = 0.f;
#pragma unroll
    for (int wi = 0; wi < 8; ++wi) e += red2[tid*8 + wi];
    eraw[m0 + tid] = e;
    float mm = e;
#pragma unroll
    for (int dd = 1; dd < 64; dd <<= 1) mm = fmaxf(mm, __shfl_xor(mm, dd, 64));
    const float pv = __expf(e - mm);
    float ss = pv;
#pragma unroll
    for (int dd = 1; dd < 64; dd <<= 1) ss += __shfl_xor(ss, dd, 64);
    pfin[tid] = pv;
    if (tid == 0) { cmax[g] = mm; csum[g] = ss; }
  }
  __syncthreads();

  // ---- epilogue 3: partial_d = sum_s p_s * A_lds[s][d], d = 2*tid, 2*tid+1 ----
  // b32 read gives the bf16 pair (d, d+1); consecutive lanes hit consecutive
  // 4B -> 2-way bank aliasing only (free). pfin[row] is a broadcast read.
  {
    const int u    = tid >> 2;          // d/8
    const int joff = (tid & 3) * 2;     // d%8
    const short* ap = Al + (size_t)u*8 + joff;
    float a0 = 0.f, a1 = 0.f;
#pragma unroll 16
    for (int row = 0; row < 64; ++row) {
      const unsigned int bits = *(const unsigned int*)(ap + (size_t)row*1032);
      const float pv = pfin[row];
      const float lo = __builtin_bit_cast(float, bits << 16);
      const float hi = __builtin_bit_cast(float, bits & 0xffff0000u);
      a0 = fmaf(pv, lo, a0);
      a1 = fmaf(pv, hi, a1);
    }
    float2 o; o.x = a0; o.y = a1;
    *(float2*)(pattn + (size_t)g*D + 2*tid) = o;
  }
#undef LOADB
#undef LOADA
#undef MFMAS
}

// ---------- Kernel 3: combine 32 chunk-partials per batch (tiny) ------------
// m_b = max_c m_c ; S_b = sum_c exp(m_c-m_b)*sumexp_c ;
// wts = exp(e-m_b)/S_b ; attn = (sum_c exp(m_c-m_b)*partial_c)/S_b.
__global__ __launch_bounds__(256) void attn_finalize(
    const float* __restrict__ eraw, const float* __restrict__ pattn,
    const float* __restrict__ cmax, const float* __restrict__ csum,
    float* __restrict__ wts, float* __restrict__ attn)
{
  const int b = blockIdx.x;
  const int t = threadIdx.x;
  __shared__ float scl[32];
  __shared__ float stats[2];

  if (t < 32) {
    const float m = cmax[b*32 + t];
    float mm = m;
#pragma unroll
    for (int dd = 1; dd < 32; dd <<= 1) mm = fmaxf(mm, __shfl_xor(mm, dd, 64));
    const float e = __expf(m - mm);
    scl[t] = e;
    float s = e * csum[b*32 + t];
#pragma unroll
    for (int dd = 1; dd < 32; dd <<= 1) s += __shfl_xor(s, dd, 64);
    if (t == 0) { stats[0] = mm; stats[1] = 1.f / s; }
  }
  __syncthreads();
  const float m_b = stats[0];
  const float inv = stats[1];

  // weights: 2048 per batch, 8 per thread
#pragma unroll
  for (int j = 0; j < 8; ++j) {
    const int s = j*256 + t;
    wts[(size_t)b*SLEN + s] = __expf(eraw[(size_t)b*SLEN + s] - m_b) * inv;
  }

  // attn: 4 cols per thread, combine 32 chunks
  float acc[4] = {0.f, 0.f, 0.f, 0.f};
#pragma unroll
  for (int c = 0; c < 32; ++c) {
    const float sc = scl[c];
    const float* pp = pattn + ((size_t)(b*32 + c))*D + t;
#pragma unroll
    for (int j = 0; j < 4; ++j)
      acc[j] = fmaf(sc, pp[j*256], acc[j]);
  }
#pragma unroll
  for (int j = 0; j < 4; ++j)
    attn[(size_t)b*D + j*256 + t] = acc[j] * inv;
}

extern "C" void kernel_launch(void* const* d_in, const int* in_sizes, int n_in,
                              void* d_out, int out_size, void* d_ws, size_t ws_size,
                              hipStream_t stream) {
  // inputs: 0=query 1=states 2=Wq 3=bq 4=Wk 5=bk 6=We 7=be
  // q-path terms are constant per softmax row -> cancel; dead code.
  const float* states = (const float*)d_in[1];
  const float* Wk     = (const float*)d_in[4];
  const float* bk     = (const float*)d_in[5];
  const float* We     = (const float*)d_in[6];
  float* out = (float*)d_out;            // [0:32768) attn_weights, [32768:49152) attn

  char* ws = (char*)d_ws;
  short* WkT   = (short*)ws;                                  ws += (size_t)D*D*sizeof(short);  // 2 MB
  float* eraw  = (float*)ws;                                  ws += (size_t)MROWS*sizeof(float); // 128 KB
  float* pattn = (float*)ws;                                  ws += (size_t)NCHUNK*D*sizeof(float); // 2 MB
  float* cmaxp = (float*)ws;                                  ws += (size_t)NCHUNK*sizeof(float);
  float* csump = (float*)ws;

  (void)in_sizes; (void)n_in; (void)out_size; (void)ws_size;

  wk_prep<<<128, 256, 0, stream>>>(Wk, WkT);
  energy_gemm<<<NCHUNK, 512, 0, stream>>>(states, WkT, bk, We, eraw, pattn, cmaxp, csump);
  attn_finalize<<<BS, 256, 0, stream>>>(eraw, pattn, cmaxp, csump, out, out + MROWS);
}